// Round 5
// baseline (239.451 us; speedup 1.0000x reference)
//
#include <hip/hip_runtime.h>
#include <math.h>

// Problem constants (B=1)
#define NTOK 4096
#define EMB  256
#define NH   4
#define HD   64

typedef unsigned short u16;
typedef __attribute__((ext_vector_type(8))) __bf16 bf16x8;
typedef __attribute__((ext_vector_type(4))) float f32x4;

__device__ __forceinline__ u16 f2bf(float f) {
    union { float f; unsigned u; } v; v.f = f;
    unsigned b = v.u;
    b += 0x7FFFu + ((b >> 16) & 1u);     // round-nearest-even
    return (u16)(b >> 16);
}
__device__ __forceinline__ float bf2f(u16 u) {
    union { unsigned u; float f; } v; v.u = ((unsigned)u) << 16;
    return v.f;
}

// ---------------------------------------------------------------------------
// prep = w4cast + xcast fused (grid-partitioned).
// blocks [0,640): 4 fp32 weight tensors -> concat bf16 wb.
//   segments (float4 units): Wqkv 49152 | out_w 16384 | ffn1 65536 | ffn2 32768
// blocks [640,1664): x fp32 -> xb bf16 AND catb[:, :256] (row stride 512).
// ---------------------------------------------------------------------------
__global__ __launch_bounds__(256) void prep(
    const float4* __restrict__ w0, const float4* __restrict__ w1,
    const float4* __restrict__ w2, const float4* __restrict__ w3,
    u16* __restrict__ wb,
    const float4* __restrict__ x4, u16* __restrict__ xb, u16* __restrict__ catb)
{
    const int bid = blockIdx.x;
    if (bid < 640) {
        const int f = bid * 256 + threadIdx.x;   // < 163840
        float4 v;
        if      (f <  49152) v = w0[f];
        else if (f <  65536) v = w1[f - 49152];
        else if (f < 131072) v = w2[f - 65536];
        else                 v = w3[f - 131072];
        uint2 o;
        o.x = (unsigned)f2bf(v.x) | ((unsigned)f2bf(v.y) << 16);
        o.y = (unsigned)f2bf(v.z) | ((unsigned)f2bf(v.w) << 16);
        *(uint2*)(wb + (size_t)f * 4) = o;
    } else {
        const int f = (bid - 640) * 256 + threadIdx.x;   // < 262144
        float4 v = x4[f];
        uint2 o;
        o.x = (unsigned)f2bf(v.x) | ((unsigned)f2bf(v.y) << 16);
        o.y = (unsigned)f2bf(v.z) | ((unsigned)f2bf(v.w) << 16);
        *(uint2*)(xb + (size_t)f * 4) = o;
        const int row = f >> 6, c = (f & 63) * 4;
        *(uint2*)(catb + (size_t)row * 512 + c) = o;
    }
}

// ---------------------------------------------------------------------------
// bf16 MFMA GEMM: C[m][n] = sum_k A[m][k]*B[n][k] + bias[n] (+resid).
// Block 256 thr / 4 waves; tile 64(M)x64(N); wave w owns rows w*16..+15.
// Fragments (HW-verified): A[row=li][k=lg*8+j], B[col=li][k=lg*8+j],
// D[row=lg*4+p][col=li]. No LDS (operands L1/L2-resident at these sizes).
// ---------------------------------------------------------------------------
__global__ __launch_bounds__(256) void gemm_bf16_abt(
    const u16* __restrict__ A,     // [M][K] bf16
    const u16* __restrict__ B,     // [N][K] bf16
    const float* __restrict__ bias,
    const float* __restrict__ resid, int ldr,   // may be null
    float* __restrict__ Cf, u16* __restrict__ Cb, int ldc, int K)
{
    const int t = threadIdx.x, w = t >> 6, l = t & 63;
    const int lg = l >> 4, li = l & 15;
    const int row0 = blockIdx.y * 64 + w * 16;
    const int col0 = blockIdx.x * 64;

    f32x4 acc[4];
    #pragma unroll
    for (int nb = 0; nb < 4; ++nb) acc[nb] = (f32x4){0.f, 0.f, 0.f, 0.f};

    const u16* Ap = A + (size_t)(row0 + li) * K + lg * 8;
    const u16* Bp = B + (size_t)(col0 + li) * K + lg * 8;

    #pragma unroll 2
    for (int k0 = 0; k0 < K; k0 += 32) {
        bf16x8 a = *(const bf16x8*)(Ap + k0);
        #pragma unroll
        for (int nb = 0; nb < 4; ++nb) {
            bf16x8 b = *(const bf16x8*)(Bp + (size_t)nb * 16 * K + k0);
            acc[nb] = __builtin_amdgcn_mfma_f32_16x16x32_bf16(a, b, acc[nb], 0, 0, 0);
        }
    }

    #pragma unroll
    for (int nb = 0; nb < 4; ++nb) {
        const int col = col0 + nb * 16 + li;
        const float bs = bias[col];
        #pragma unroll
        for (int p = 0; p < 4; ++p) {
            const int row = row0 + lg * 4 + p;
            float v = acc[nb][p] + bs;
            if (resid) v += resid[(size_t)row * ldr + col];
            if (Cf) Cf[(size_t)row * ldc + col] = v;
            else    Cb[(size_t)row * ldc + col] = f2bf(v);
        }
    }
}

// ---------------------------------------------------------------------------
// qkv_post = rope_qk + v_transpose fused (grid-partitioned).
// blocks [0,2048): RoPE -> bf16 Q (x0.125) and K, layout [h][n][64].
// blocks [2048,2304): V slot -> bf16 transposed Vt[h][d][key].
// qkvb row layout per n: h*192 + d*3 + {0:q,1:k,2:v}.
// ---------------------------------------------------------------------------
__global__ __launch_bounds__(256) void qkv_post(
    const u16* __restrict__ qkvb, const float* __restrict__ enc,
    unsigned* __restrict__ Qb, unsigned* __restrict__ Kb, u16* __restrict__ Vt)
{
    const int bid = blockIdx.x;
    if (bid < 2048) {
        const int gid = bid * 256 + threadIdx.x;   // NH*NTOK*32
        const int h   = gid >> 17;
        const int rem = gid & (NTOK * 32 - 1);
        const int n   = rem >> 5;
        const int p   = rem & 31;
        const int d0  = p * 2;

        const u16* base = qkvb + (size_t)n * 768 + h * 192 + d0 * 3;
        const float q0v = bf2f(base[0]), k0 = bf2f(base[1]);
        const float q1  = bf2f(base[3]), k1 = bf2f(base[4]);

        float2 c01 = *(const float2*)(enc + (size_t)n * 64 + d0);
        float2 s01 = *(const float2*)(enc + (size_t)NTOK * 64 + (size_t)n * 64 + d0);

        const float qo0 = (q0v * c01.x - q1 * s01.x) * 0.125f;
        const float qo1 = (q1 * c01.y + q0v * s01.y) * 0.125f;
        const float ko0 = k0 * c01.x - k1 * s01.x;
        const float ko1 = k1 * c01.y + k0 * s01.y;

        const size_t oidx = ((size_t)(h * NTOK + n) << 5) + p;
        Qb[oidx] = (unsigned)f2bf(qo0) | ((unsigned)f2bf(qo1) << 16);
        Kb[oidx] = (unsigned)f2bf(ko0) | ((unsigned)f2bf(ko1) << 16);
    } else {
        const int vb = bid - 2048;
        const int h  = vb >> 6;
        const int nt = vb & 63;
        const int t  = threadIdx.x;
        const int d  = t & 63;
        const int nc = t >> 6;   // 0..3

        __align__(16) u16 us[16];
        #pragma unroll
        for (int i = 0; i < 16; ++i) {
            const int n = nt * 64 + nc * 16 + i;
            us[i] = qkvb[(size_t)n * 768 + h * 192 + d * 3 + 2];
        }
        u16* dst = Vt + ((size_t)(h * 64 + d) << 12) + nt * 64 + nc * 16;
        *(uint4*)(dst)     = *(uint4*)(us);
        *(uint4*)(dst + 8) = *(uint4*)(us + 8);
    }
}

// ---------------------------------------------------------------------------
// Flash attention v3, bf16 MFMA. q-tile 32; 8 waves/block, wave wk owns keys
// [wk*512, wk*512+512) over ALL 32 q-rows. Grid (128 q-tiles, 4 heads) = 512
// blocks x 8 waves = 4096 waves -> 16 waves/CU (50% occ; was 25%).
// l kept LANE-PARTIAL through the main loop (corr is row-uniform), reduced
// once at the end — removes the per-tile 4-step shfl-add.
// P via per-wave 4KB LDS tile, 16B-slot XOR swizzle. Cross-wk merge via LDS.
// ---------------------------------------------------------------------------
__global__ __launch_bounds__(512, 2) void flash_attn_v3(
    const u16* __restrict__ Qb, const u16* __restrict__ Kb,
    const u16* __restrict__ Vt, u16* __restrict__ ctxb)
{
    __shared__ char  Plds[8 * 4096];
    __shared__ float Obuf[32 * 64];
    __shared__ float Mbuf[32], Lbuf[32];

    const int t  = threadIdx.x;
    const int wk = t >> 6;              // 0..7: key-eighth
    const int l  = t & 63;
    const int lg = l >> 4, li = l & 15;
    const int h  = blockIdx.y;
    const int q0 = blockIdx.x * 32;

    char* Pw = Plds + wk * 4096;

    // Q fragments: rows q0 + Mb*16 + li, d = kh*32 + lg*8 + {0..7}
    bf16x8 QA[2][2];
    #pragma unroll
    for (int Mb = 0; Mb < 2; ++Mb)
        #pragma unroll
        for (int kh = 0; kh < 2; ++kh)
            QA[Mb][kh] = *(const bf16x8*)(Qb +
                ((size_t)(h * NTOK + q0 + Mb * 16 + li) << 6) + kh * 32 + lg * 8);

    f32x4 OA[2][4];
    float mrun[2][4], lrun[2][4];   // lrun is LANE-PARTIAL until the end
    #pragma unroll
    for (int Mb = 0; Mb < 2; ++Mb) {
        #pragma unroll
        for (int p = 0; p < 4; ++p) { mrun[Mb][p] = -1e30f; lrun[Mb][p] = 0.f; }
        #pragma unroll
        for (int db = 0; db < 4; ++db) OA[Mb][db] = (f32x4){0.f, 0.f, 0.f, 0.f};
    }

    for (int it = 0; it < 8; ++it) {
        const int kt = (wk << 9) + (it << 6);

        bf16x8 KB[4][2], VB[4][2];
        #pragma unroll
        for (int kb = 0; kb < 4; ++kb)
            #pragma unroll
            for (int kh = 0; kh < 2; ++kh)
                KB[kb][kh] = *(const bf16x8*)(Kb +
                    ((size_t)(h * NTOK + kt + kb * 16 + li) << 6) + kh * 32 + lg * 8);
        #pragma unroll
        for (int db = 0; db < 4; ++db)
            #pragma unroll
            for (int kh = 0; kh < 2; ++kh)
                VB[db][kh] = *(const bf16x8*)(Vt +
                    ((size_t)(h * 64 + db * 16 + li) << 12) + kt + kh * 32 + lg * 8);

        // ---- scores ----
        f32x4 SA[2][4];
        #pragma unroll
        for (int Mb = 0; Mb < 2; ++Mb)
            #pragma unroll
            for (int kb = 0; kb < 4; ++kb) {
                f32x4 z = (f32x4){0.f, 0.f, 0.f, 0.f};
                z = __builtin_amdgcn_mfma_f32_16x16x32_bf16(QA[Mb][0], KB[kb][0], z, 0, 0, 0);
                SA[Mb][kb] = __builtin_amdgcn_mfma_f32_16x16x32_bf16(QA[Mb][1], KB[kb][1], z, 0, 0, 0);
            }

        // ---- online softmax (rows in (lg,p); max-reduce over 16 li lanes) ----
        #pragma unroll
        for (int Mb = 0; Mb < 2; ++Mb)
            #pragma unroll
            for (int p = 0; p < 4; ++p) {
                float mx = fmaxf(fmaxf(SA[Mb][0][p], SA[Mb][1][p]),
                                 fmaxf(SA[Mb][2][p], SA[Mb][3][p]));
                #pragma unroll
                for (int sh = 1; sh < 16; sh <<= 1)
                    mx = fmaxf(mx, __shfl_xor(mx, sh));
                const float mo = mrun[Mb][p];
                const float mn = fmaxf(mo, mx);
                const float corr = __expf(mo - mn);
                mrun[Mb][p] = mn;
                float pv[4], ps = 0.f;
                #pragma unroll
                for (int kb = 0; kb < 4; ++kb) {
                    pv[kb] = __expf(SA[Mb][kb][p] - mn);
                    ps += pv[kb];
                }
                lrun[Mb][p] = lrun[Mb][p] * corr + ps;   // lane-partial
                #pragma unroll
                for (int db = 0; db < 4; ++db) OA[Mb][db][p] *= corr;

                const int ql = Mb * 16 + lg * 4 + p;   // 0..31
                #pragma unroll
                for (int kb = 0; kb < 4; ++kb) {
                    const int kl = kb * 16 + li;
                    *(u16*)(Pw + ql * 128 + ((kl * 2) ^ ((ql & 7) << 4))) = f2bf(pv[kb]);
                }
            }

        // ---- PV (per-wave in-order DS: writes above complete before reads) ----
        #pragma unroll
        for (int Mb = 0; Mb < 2; ++Mb)
            #pragma unroll
            for (int kh = 0; kh < 2; ++kh) {
                const int ql = Mb * 16 + li;
                bf16x8 PA = *(const bf16x8*)(Pw + ql * 128 +
                                ((kh * 64 + lg * 16) ^ ((ql & 7) << 4)));
                #pragma unroll
                for (int db = 0; db < 4; ++db)
                    OA[Mb][db] = __builtin_amdgcn_mfma_f32_16x16x32_bf16(
                        PA, VB[db][kh], OA[Mb][db], 0, 0, 0);
            }
    }

    // ---- finalize l: one 16-lane reduce per row ----
    #pragma unroll
    for (int Mb = 0; Mb < 2; ++Mb)
        #pragma unroll
        for (int p = 0; p < 4; ++p) {
            float ps = lrun[Mb][p];
            #pragma unroll
            for (int sh = 1; sh < 16; sh <<= 1) ps += __shfl_xor(ps, sh);
            lrun[Mb][p] = ps;
        }

    // ---- cross-wk online-softmax merge (wave-serialized through LDS) ----
    if (wk == 0) {
        #pragma unroll
        for (int Mb = 0; Mb < 2; ++Mb)
            #pragma unroll
            for (int p = 0; p < 4; ++p) {
                const int q = Mb * 16 + lg * 4 + p;
                #pragma unroll
                for (int db = 0; db < 4; ++db)
                    Obuf[q * 64 + db * 16 + li] = OA[Mb][db][p];
                if (li == 0) { Mbuf[q] = mrun[Mb][p]; Lbuf[q] = lrun[Mb][p]; }
            }
    }
    #pragma unroll
    for (int wv = 1; wv < 8; ++wv) {
        __syncthreads();
        if (wk == wv) {
            #pragma unroll
            for (int Mb = 0; Mb < 2; ++Mb)
                #pragma unroll
                for (int p = 0; p < 4; ++p) {
                    const int q = Mb * 16 + lg * 4 + p;
                    const float Mo = Mbuf[q], Lo = Lbuf[q];
                    const float mn = fmaxf(Mo, mrun[Mb][p]);
                    const float a  = __expf(Mo - mn);
                    const float b  = __expf(mrun[Mb][p] - mn);
                    #pragma unroll
                    for (int db = 0; db < 4; ++db) {
                        const int idx = q * 64 + db * 16 + li;
                        Obuf[idx] = Obuf[idx] * a + OA[Mb][db][p] * b;
                    }
                    if (li == 0) { Mbuf[q] = mn; Lbuf[q] = Lo * a + lrun[Mb][p] * b; }
                }
        }
    }
    __syncthreads();

    // ---- write ctx bf16 (N, E): 512 thr x 4 d = 32x64 ----
    {
        const int q = t >> 4, dc = (t & 15) * 4;
        const float rl = 1.f / Lbuf[q];
        uint2 ov;
        ov.x = (unsigned)f2bf(Obuf[q * 64 + dc + 0] * rl) |
               ((unsigned)f2bf(Obuf[q * 64 + dc + 1] * rl) << 16);
        ov.y = (unsigned)f2bf(Obuf[q * 64 + dc + 2] * rl) |
               ((unsigned)f2bf(Obuf[q * 64 + dc + 3] * rl) << 16);
        *(uint2*)(ctxb + (size_t)(q0 + q) * EMB + h * 64 + dc) = ov;
    }
}

// ---------------------------------------------------------------------------
// Row LayerNorm(512) + exact GeLU; fp32 in, bf16 out.
// ---------------------------------------------------------------------------
__global__ __launch_bounds__(256) void ln_gelu(
    const float* __restrict__ h1, const float* __restrict__ g,
    const float* __restrict__ b, u16* __restrict__ h2b)
{
    __shared__ float red[8];
    const int row = blockIdx.x, t = threadIdx.x;
    const float v0 = h1[(size_t)row * 512 + t];
    const float v1 = h1[(size_t)row * 512 + 256 + t];

    float s = v0 + v1;
    #pragma unroll
    for (int w = 1; w < 64; w <<= 1) s += __shfl_xor(s, w);
    if ((t & 63) == 0) red[t >> 6] = s;
    __syncthreads();
    const float mu = (red[0] + red[1] + red[2] + red[3]) * (1.f / 512.f);

    const float d0 = v0 - mu, d1 = v1 - mu;
    float vs = d0 * d0 + d1 * d1;
    #pragma unroll
    for (int w = 1; w < 64; w <<= 1) vs += __shfl_xor(vs, w);
    if ((t & 63) == 0) red[4 + (t >> 6)] = vs;
    __syncthreads();
    const float var  = (red[4] + red[5] + red[6] + red[7]) * (1.f / 512.f);
    const float rstd = rsqrtf(var + 1e-5f);

    const float y0 = d0 * rstd * g[t] + b[t];
    const float y1 = d1 * rstd * g[t + 256] + b[t + 256];
    const float o0 = 0.5f * y0 * (1.f + erff(y0 * 0.70710678118654752f));
    const float o1 = 0.5f * y1 * (1.f + erff(y1 * 0.70710678118654752f));
    h2b[(size_t)row * 512 + t]       = f2bf(o0);
    h2b[(size_t)row * 512 + 256 + t] = f2bf(o1);
}

// ---------------------------------------------------------------------------
extern "C" void kernel_launch(void* const* d_in, const int* in_sizes, int n_in,
                              void* d_out, int out_size, void* d_ws, size_t ws_size,
                              hipStream_t stream)
{
    const float* x      = (const float*)d_in[0];
    const float* enc    = (const float*)d_in[1];
    const float* Wqkv_w = (const float*)d_in[2];
    const float* Wqkv_b = (const float*)d_in[3];
    const float* out_w  = (const float*)d_in[4];
    const float* out_b  = (const float*)d_in[5];
    const float* ffn1_w = (const float*)d_in[6];
    const float* ffn1_b = (const float*)d_in[7];
    const float* ln_g   = (const float*)d_in[8];
    const float* ln_b   = (const float*)d_in[9];
    const float* ffn2_w = (const float*)d_in[10];
    const float* ffn2_b = (const float*)d_in[11];
    float* out = (float*)d_out;
    float* ws  = (float*)d_ws;

    // workspace layout (float units), peak 6,619,136 fu = 25.9 MiB (unchanged)
    u16*   catb = (u16*)(ws);
    u16*   wb   = (u16*)(ws + 1048576);
    u16*   Qb   = (u16*)(ws + 1376256);
    u16*   Kb   = (u16*)(ws + 1900544);
    u16*   Vt   = (u16*)(ws + 2424832);
    u16*   ctxb = (u16*)(ws + 2949120);
    u16*   qkvb = (u16*)(ws + 3473408);
    float* h1   = ws + 3473408;
    u16*   xb   = (u16*)(ws + 5570560);
    u16*   h2b  = (u16*)(ws + 5570560);

    u16* Wqkvb = wb;
    u16* outwb = wb + 196608;
    u16* ffn1b = wb + 262144;
    u16* ffn2b = wb + 524288;

    // 1. casts (w4cast + xcast fused)
    prep<<<1664, 256, 0, stream>>>((const float4*)Wqkv_w, (const float4*)out_w,
                                   (const float4*)ffn1_w, (const float4*)ffn2_w, wb,
                                   (const float4*)x, xb, catb);
    // 2. QKV projection: (4096,256)@(768,256)^T -> bf16 qkvb
    gemm_bf16_abt<<<dim3(12, 64), 256, 0, stream>>>(xb, Wqkvb, Wqkv_b,
                                                    nullptr, 0, nullptr, qkvb, 768, 256);
    // 3. RoPE + V-transpose (fused)
    qkv_post<<<2304, 256, 0, stream>>>(qkvb, enc, (unsigned*)Qb, (unsigned*)Kb, Vt);
    // 4. attention -> ctxb bf16
    flash_attn_v3<<<dim3(128, NH), 512, 0, stream>>>(Qb, Kb, Vt, ctxb);
    // 5. out_proj -> catb[:, 256:]
    gemm_bf16_abt<<<dim3(4, 64), 256, 0, stream>>>(ctxb, outwb, out_b,
                                                   nullptr, 0, nullptr, catb + 256, 512, 256);
    // 6. FFN1 -> h1 fp32
    gemm_bf16_abt<<<dim3(8, 64), 256, 0, stream>>>(catb, ffn1b, ffn1_b,
                                                   nullptr, 0, h1, nullptr, 512, 512);
    // 7. LayerNorm + GeLU -> h2b bf16
    ln_gelu<<<4096, 256, 0, stream>>>(h1, ln_g, ln_b, h2b);
    // 8. FFN2 + residual -> out fp32
    gemm_bf16_abt<<<dim3(4, 64), 256, 0, stream>>>(h2b, ffn2b, ffn2_b,
                                                   x, 256, out, nullptr, 256, 512);
}